// Round 11
// baseline (234.421 us; speedup 1.0000x reference)
//
#include <hip/hip_runtime.h>
#include <stdint.h>

// irreps linear: 128x0e+128x1o+128x2e, per-block y[z,w,i] = a * sum_u W[u,w] x[z,u,i]
// GEMMs with M=(i,z), N=w(128), K=u(128). bf16 MFMA, f32 accum.
// Structure = round-6/8 best (201 us): persistent WGs (1024 = 4/CU), W in
// registers, double-buffered LDS x, register prefetch issued before MFMA and
// consumed after, dense per-lane non-temporal stores, ONE __syncthreads/tile.
// r11 = r10 with the compile fix (if constexpr dispatch): D=3/5 global loads
// are per-instruction COALESCED (half-wave covers 512 contiguous bytes/instr)
// instead of lane-stride 4D*4B (which touched ~5x the cache lines per
// instruction = TA/L1 request inflation, invisible in FETCH/WRITE bytes).
// The u/i deinterleave moves into the LDS-write address computation
// (compile-time magic div/mod by D, ds_write_b16).

#define NROWS 100000
#define ROWLEN 1152

typedef __attribute__((ext_vector_type(8))) short bf16x8;
typedef __attribute__((ext_vector_type(4))) float f32x4;
typedef __attribute__((ext_vector_type(4))) ushort u16x4;
typedef float f32x4u __attribute__((ext_vector_type(4), aligned(4)));
typedef float f32x2u __attribute__((ext_vector_type(2), aligned(4)));

__device__ __forceinline__ ushort f2b(float f) {
  union { float f; uint32_t u; } v; v.f = f;
  uint32_t r = v.u + 0x7FFFu + ((v.u >> 16) & 1u);  // RNE; inputs finite
  return (ushort)(r >> 16);
}

// ---- D=1 staging (already coalesced): chunk = 4 consecutive u, same m -----
template<int TM, bool G>
__device__ __forceinline__ void load_tile1(const float* __restrict__ xb, int t,
                                           int tid, f32x4 (&vf)[TM / 8][1])
{
  #pragma unroll
  for (int p = 0; p < TM / 8; ++p) {
    int ch = p * 256 + tid;
    int zl = ch >> 5, cc = ch & 31;
    int z  = t * TM + zl;
    f32x4 v = {0.f, 0.f, 0.f, 0.f};
    if (!G || z < NROWS) v = *(const f32x4*)(xb + (size_t)z * ROWLEN + cc * 4);
    vf[p][0] = v;
  }
}

template<int TM>
__device__ __forceinline__ void write_tile1(char* __restrict__ buf, int tid,
                                            f32x4 (&vf)[TM / 8][1])
{
  #pragma unroll
  for (int p = 0; p < TM / 8; ++p) {
    int ch = p * 256 + tid;
    int zl = ch >> 5, cc = ch & 31;   // m = zl, u-chunk base = cc*4
    u16x4 pk;
    #pragma unroll
    for (int u = 0; u < 4; ++u) pk[u] = f2b(vf[p][0][u]);
    int byte = zl * 256 + ((((cc >> 1) ^ (zl & 7)) << 4) | ((cc & 1) << 3));
    *(u16x4*)(buf + byte) = pk;
  }
}

// ---- D=3/5 staging, coalesced loads (TM = 16) -----------------------------
// Instruction j: lane l31 loads 16B at row-chunk (j*32 + l31) -> half-wave
// covers 512 contiguous bytes. LDS A layout unchanged: [m][u] bf16, row 256B,
// 16B-chunk XOR swizzle chunk^=(m&7); m = i*16 + zl, element e = u*D + i.
template<int D, bool G>
__device__ __forceinline__ void load_tile_c(const float* __restrict__ xb, int t,
                                            int tid, f32x4 (&vf)[2][D])
{
  const int l31 = tid & 31;
  #pragma unroll
  for (int p = 0; p < 2; ++p) {
    int zl = p * 8 + (tid >> 5);
    int z  = t * 16 + zl;
    const float* src = xb + (size_t)z * ROWLEN + l31 * 4;
    #pragma unroll
    for (int j = 0; j < D; ++j) {
      f32x4 v = {0.f, 0.f, 0.f, 0.f};
      if (!G || z < NROWS) v = *(const f32x4*)(src + j * 128);
      vf[p][j] = v;
    }
  }
}

template<int D>
__device__ __forceinline__ void write_tile_c(char* __restrict__ buf, int tid,
                                             f32x4 (&vf)[2][D])
{
  const unsigned l31 = tid & 31;
  #pragma unroll
  for (int p = 0; p < 2; ++p) {
    const int zl = p * 8 + (tid >> 5);
    #pragma unroll
    for (int j = 0; j < D; ++j) {
      #pragma unroll
      for (int k = 0; k < 4; ++k) {
        unsigned e = (j * 32 + l31) * 4 + (unsigned)k;  // float idx in row
        unsigned u = e / (unsigned)D;                   // magic-div (D const)
        unsigned i = e - u * (unsigned)D;
        int m = (int)i * 16 + zl;
        int byte = m * 256 +
                   (((((int)u >> 3) ^ (m & 7)) << 4) | (((int)u & 7) << 1));
        *(ushort*)(buf + byte) = f2b(vf[p][j][k]);
      }
    }
  }
}

// ---- stores (non-temporal: out is write-once, never re-read) -------------
template<bool G, int TM, int MTILES>
__device__ __forceinline__ void store_d1(float* __restrict__ ob, int z0,
                                         int lane, int nbase,
                                         f32x4 (&acc)[MTILES][2])
{
  const int rbase = ((lane >> 4) & 3) << 2;
  #pragma unroll
  for (int mt = 0; mt < MTILES; ++mt) {
    #pragma unroll
    for (int r = 0; r < 4; ++r) {
      int zl = mt * 16 + rbase + r;
      int z  = z0 + zl;
      if (G && z >= NROWS) continue;
      float* orow = ob + (size_t)z * ROWLEN;
      __builtin_nontemporal_store(acc[mt][0][r], orow + nbase);
      __builtin_nontemporal_store(acc[mt][1][r], orow + nbase + 16);
    }
  }
}

// TM=16 paths: lane holds all D consecutive cols (i == mt) for its (n, z).
template<int D, int MTILES>
__device__ __forceinline__ void store_dense(float* __restrict__ ob, int z0,
                                            int lane, int nbase,
                                            f32x4 (&acc)[MTILES][2])
{
  const int rbase = ((lane >> 4) & 3) << 2;
  #pragma unroll
  for (int nt = 0; nt < 2; ++nt) {
    const int colb = (nbase + nt * 16) * D;
    #pragma unroll
    for (int r = 0; r < 4; ++r) {
      int z = z0 + rbase + r;
      float* p = ob + (size_t)z * ROWLEN + colb;
      if constexpr (D == 5) {
        f32x4u v4 = { acc[0][nt][r], acc[1][nt][r], acc[2][nt][r], acc[3][nt][r] };
        __builtin_nontemporal_store(v4, (f32x4u*)p);
        __builtin_nontemporal_store(acc[4][nt][r], p + 4);
      } else {  // D == 3
        f32x2u v2 = { acc[0][nt][r], acc[1][nt][r] };
        __builtin_nontemporal_store(v2, (f32x2u*)p);
        __builtin_nontemporal_store(acc[2][nt][r], p + 2);
      }
    }
  }
}

// ---- persistent per-irrep path ------------------------------------------
template<int D, int TM, bool GUARD, int NWGS>
__device__ __forceinline__ void linpath(const float* __restrict__ xb,
                                        const float* __restrict__ wb,
                                        float* __restrict__ ob,
                                        int wgid, char* lds)
{
  constexpr int MT     = TM * D;
  constexpr int MTILES = MT / 16;
  constexpr int PT     = TM / 8;
  constexpr int NTILES = (NROWS + TM - 1) / TM;
  constexpr int BUFB   = MT * 256;
  constexpr float ALPHA = 0.088388347648318447f;  // 128^-0.5

  const int tid   = threadIdx.x;
  const int lane  = tid & 63;
  const int wv    = tid >> 6;
  const int l15   = lane & 15;
  const int kr    = ((lane >> 4) & 3) << 3;
  const int nbase = (wv << 5) + l15;

  // weights -> registers once per WG (K=128 x N=32 per wave), ALPHA folded
  bf16x8 bfr[2][4];
  #pragma unroll
  for (int nt = 0; nt < 2; ++nt)
    #pragma unroll
    for (int ks = 0; ks < 4; ++ks)
      #pragma unroll
      for (int j = 0; j < 8; ++j)
        bfr[nt][ks][j] =
            (short)f2b(wb[(ks * 32 + kr + j) * 128 + nbase + nt * 16] * ALPHA);

  char* buf0 = lds;
  char* buf1 = lds + BUFB;

  // prologue: stage first tile
  int t0 = wgid;
  {
    f32x4 vf[PT][D];
    if constexpr (D == 1) {
      if (GUARD && t0 == NTILES - 1) load_tile1<TM, true>(xb, t0, tid, vf);
      else                           load_tile1<TM, false>(xb, t0, tid, vf);
      write_tile1<TM>(buf0, tid, vf);
    } else {
      load_tile_c<D, false>(xb, t0, tid, vf);
      write_tile_c<D>(buf0, tid, vf);
    }
  }
  __syncthreads();

  int cur = 0;
  for (int t = t0; t < NTILES; t += NWGS) {
    char* bc = cur ? buf1 : buf0;
    char* bn = cur ? buf0 : buf1;
    const int tn = t + NWGS;
    const bool have = tn < NTILES;

    // 1. issue next tile's global loads into regs (latency hides under MFMA)
    f32x4 vf[PT][D];
    if (have) {
      if constexpr (D == 1) {
        if (GUARD && tn == NTILES - 1) load_tile1<TM, true>(xb, tn, tid, vf);
        else                           load_tile1<TM, false>(xb, tn, tid, vf);
      } else {
        load_tile_c<D, false>(xb, tn, tid, vf);
      }
    }

    // 2. MFMA on current buffer
    f32x4 acc[MTILES][2];
    #pragma unroll
    for (int mt = 0; mt < MTILES; ++mt) {
      acc[mt][0] = f32x4{0.f, 0.f, 0.f, 0.f};
      acc[mt][1] = f32x4{0.f, 0.f, 0.f, 0.f};
    }
    #pragma unroll
    for (int ks = 0; ks < 4; ++ks) {
      const int chunkbase = ks * 4 + ((lane >> 4) & 3);  // (ks*32+kr)>>3
      #pragma unroll
      for (int mt = 0; mt < MTILES; ++mt) {
        int m = (mt << 4) + l15;
        int byte = m * 256 + ((chunkbase ^ (m & 7)) << 4);
        bf16x8 a = *(const bf16x8*)(bc + byte);
        acc[mt][0] = __builtin_amdgcn_mfma_f32_16x16x32_bf16(a, bfr[0][ks], acc[mt][0], 0, 0, 0);
        acc[mt][1] = __builtin_amdgcn_mfma_f32_16x16x32_bf16(a, bfr[1][ks], acc[mt][1], 0, 0, 0);
      }
    }

    // 3. convert + LDS-write next tile (global loads have landed by now)
    if (have) {
      if constexpr (D == 1) write_tile1<TM>(bn, tid, vf);
      else                  write_tile_c<D>(bn, tid, vf);
    }

    // 4. store current tile's output (dense per-lane spans, non-temporal)
    if constexpr (D == 1) {
      if (GUARD && t == NTILES - 1)
        store_d1<true, TM, MTILES>(ob, t * TM, lane, nbase, acc);
      else
        store_d1<false, TM, MTILES>(ob, t * TM, lane, nbase, acc);
    } else {
      store_dense<D, MTILES>(ob, t * TM, lane, nbase, acc);
    }

    __syncthreads();
    cur ^= 1;
  }
}

// WG split proportional to bytes (1:3:5), grid = 1024 = 4 WGs/CU.
constexpr int NW1 = 114;   // D=1, TM=64, 1563 tiles
constexpr int NW3 = 341;   // D=3, TM=16, 6250 tiles
constexpr int NW5 = 569;   // D=5, TM=16, 6250 tiles

__global__ __launch_bounds__(256, 4)
void linear_irreps_kernel(const float* __restrict__ x, const float* __restrict__ w,
                          float* __restrict__ out)
{
  extern __shared__ __align__(16) char lds[];
  int wg = blockIdx.x;
  if (wg < NW1) {
    linpath<1, 64, true,  NW1>(x,       w,         out,       wg,             lds);
  } else if (wg < NW1 + NW3) {
    linpath<3, 16, false, NW3>(x + 128, w + 16384, out + 128, wg - NW1,       lds);
  } else {
    linpath<5, 16, false, NW5>(x + 512, w + 32768, out + 512, wg - NW1 - NW3, lds);
  }
}

extern "C" void kernel_launch(void* const* d_in, const int* in_sizes, int n_in,
                              void* d_out, int out_size, void* d_ws, size_t ws_size,
                              hipStream_t stream) {
  const float* x = (const float*)d_in[0];
  const float* w = (const float*)d_in[1];
  float* out = (float*)d_out;
  (void)in_sizes; (void)n_in; (void)out_size; (void)d_ws; (void)ws_size;
  dim3 grid(NW1 + NW3 + NW5);
  dim3 block(256);
  hipLaunchKernelGGL(linear_irreps_kernel, grid, block, 40960, stream, x, w, out);
}

// Round 12
// 197.920 us; speedup vs baseline: 1.1844x; 1.1844x over previous
//
#include <hip/hip_runtime.h>
#include <stdint.h>

// irreps linear: 128x0e+128x1o+128x2e, per-block y[z,w,i] = a * sum_u W[u,w] x[z,u,i]
// r12: FUSED full-row WGs. One 1024-thread WG owns 16 complete rows per tile:
// reads 73.7KB contiguous, writes 73.7KB contiguous (previously the 3 irrep
// paths hit disjoint column bands of each DRAM row from different CUs at
// different times -> ~3x row activations; the one lever not yet tested).
// Per-instruction load/LDS patterns are identical to the 201us r6 kernel.
// 16 waves/CU (1 WG/CU), W in regs, dbuf LDS, prefetch before MFMA, dense NT
// stores, one __syncthreads per tile.

#define NROWS 100000
#define ROWLEN 1152

typedef __attribute__((ext_vector_type(8))) short bf16x8;
typedef __attribute__((ext_vector_type(4))) float f32x4;
typedef __attribute__((ext_vector_type(4))) ushort u16x4;
typedef float f32x4u __attribute__((ext_vector_type(4), aligned(4)));
typedef float f32x2u __attribute__((ext_vector_type(2), aligned(4)));

__device__ __forceinline__ ushort f2b(float f) {
  union { float f; uint32_t u; } v; v.f = f;
  uint32_t r = v.u + 0x7FFFu + ((v.u >> 16) & 1u);  // RNE; inputs finite
  return (ushort)(r >> 16);
}

constexpr int TM     = 16;
constexpr int NTILES = NROWS / TM;   // 6250 exactly -> no guards anywhere
constexpr int NWGS   = 256;          // 1 WG/CU
constexpr int BUFB   = 144 * 256;    // 36864 B: 144 m-rows (16 D1 + 48 D3 + 80 D5)
constexpr float ALPHA = 0.088388347648318447f;  // 128^-0.5

// LDS byte for (m-row, 4-u chunk cc in 0..31), 8B granule; 16B-chunk XOR swizzle.
__device__ __forceinline__ int lbyte8(int m, int cc) {
  return m * 256 + ((((cc >> 1) ^ (m & 7)) << 4) | ((cc & 1) << 3));
}

// ---- staging: class A (tid<512): one D1 group + one D3 group; class B: one D5
// group. Group g: row szl = g>>5, u-chunk cc = g&31. Same per-lane patterns as r6.
__device__ __forceinline__ void stage_load(const float* __restrict__ x, int t,
                                           bool clb, int szl, int scc,
                                           f32x4 (&vf)[5])
{
  const float* row = x + (size_t)(t * TM + szl) * ROWLEN;
  if (!clb) {
    vf[0] = *(const f32x4*)(row + scc * 4);            // D1: u = 4cc..4cc+3
    const float* r3 = row + 128 + scc * 12;            // D3: 12 floats
    vf[1] = *(const f32x4*)(r3);
    vf[2] = *(const f32x4*)(r3 + 4);
    vf[3] = *(const f32x4*)(r3 + 8);
  } else {
    const float* r5 = row + 512 + scc * 20;            // D5: 20 floats
    #pragma unroll
    for (int j = 0; j < 5; ++j) vf[j] = *(const f32x4*)(r5 + 4 * j);
  }
}

__device__ __forceinline__ void stage_write(char* __restrict__ buf, bool clb,
                                            int szl, int scc, f32x4 (&vf)[5])
{
  if (!clb) {
    u16x4 p1;
    #pragma unroll
    for (int k = 0; k < 4; ++k) p1[k] = f2b(vf[0][k]);
    *(u16x4*)(buf + lbyte8(szl, scc)) = p1;            // D1: m = szl
    #pragma unroll
    for (int i = 0; i < 3; ++i) {                      // D3: m = 16 + i*16 + szl
      u16x4 pk;
      #pragma unroll
      for (int u = 0; u < 4; ++u) {
        int k = 3 * u + i;                             // compile-time
        pk[u] = f2b(vf[1 + (k >> 2)][k & 3]);
      }
      *(u16x4*)(buf + lbyte8(16 + i * 16 + szl, scc)) = pk;
    }
  } else {
    #pragma unroll
    for (int i = 0; i < 5; ++i) {                      // D5: m = 64 + i*16 + szl
      u16x4 pk;
      #pragma unroll
      for (int u = 0; u < 4; ++u) {
        int k = 5 * u + i;                             // compile-time
        pk[u] = f2b(vf[k >> 2][k & 3]);
      }
      *(u16x4*)(buf + lbyte8(64 + i * 16 + szl, scc)) = pk;
    }
  }
}

__global__ __launch_bounds__(1024, 4)
void linear_irreps_kernel(const float* __restrict__ x, const float* __restrict__ w,
                          float* __restrict__ out)
{
  __shared__ __align__(16) char lds[2 * BUFB];         // 73728 B

  const int tid  = threadIdx.x;
  const int lane = tid & 63;
  const int wv   = tid >> 6;            // 0..15
  const int l15  = lane & 15;
  const int kq   = (lane >> 4) & 3;
  const int kr   = kq << 3;
  const int mx7  = l15 & 7;             // (m & 7) for all m = base16 + l15
  const int h    = wv & 1;              // 0: D1+D3 m-tiles, 1: D5 m-tiles
  const int n    = ((wv >> 1) << 4) + l15;   // out/W column 0..127
  const bool clb = tid >= 512;
  const int sg   = clb ? tid - 512 : tid;
  const int szl  = sg >> 5;
  const int scc  = sg & 31;

  // ---- W -> registers once (ALPHA folded). h0: D1+D3 blocks; h1: D5 block.
  bf16x8 bfr[2][4];
  if (h == 0) {
    #pragma unroll
    for (int ks = 0; ks < 4; ++ks)
      #pragma unroll
      for (int j = 0; j < 8; ++j) {
        bfr[0][ks][j] = (short)f2b(w[(ks * 32 + kr + j) * 128 + n] * ALPHA);
        bfr[1][ks][j] = (short)f2b(w[16384 + (ks * 32 + kr + j) * 128 + n] * ALPHA);
      }
  } else {
    #pragma unroll
    for (int ks = 0; ks < 4; ++ks)
      #pragma unroll
      for (int j = 0; j < 8; ++j)
        bfr[0][ks][j] = (short)f2b(w[32768 + (ks * 32 + kr + j) * 128 + n] * ALPHA);
  }

  // ---- prologue: stage tile t0 ----
  const int t0 = blockIdx.x;
  f32x4 vf[5];
  stage_load(x, t0, clb, szl, scc, vf);
  stage_write(lds, clb, szl, scc, vf);
  __syncthreads();

  int cur = 0;
  for (int t = t0; t < NTILES; t += NWGS) {
    char* bc = lds + (cur ? BUFB : 0);
    char* bn = lds + (cur ? 0 : BUFB);
    const int tn = t + NWGS;
    const bool have = tn < NTILES;

    // 1. issue next tile's global loads (hide under MFMA)
    if (have) stage_load(x, tn, clb, szl, scc, vf);

    // 2. MFMA on current buffer
    f32x4 acc[5];
    #pragma unroll
    for (int i = 0; i < 5; ++i) acc[i] = f32x4{0.f, 0.f, 0.f, 0.f};
    if (h == 0) {
      #pragma unroll
      for (int ks = 0; ks < 4; ++ks) {
        const int cb = ((ks * 4 + kq) ^ mx7) << 4;
        bf16x8 a0 = *(const bf16x8*)(bc + (l15)       * 256 + cb);
        bf16x8 a1 = *(const bf16x8*)(bc + (16  + l15) * 256 + cb);
        bf16x8 a2 = *(const bf16x8*)(bc + (32  + l15) * 256 + cb);
        bf16x8 a3 = *(const bf16x8*)(bc + (48  + l15) * 256 + cb);
        acc[0] = __builtin_amdgcn_mfma_f32_16x16x32_bf16(a0, bfr[0][ks], acc[0], 0, 0, 0);
        acc[1] = __builtin_amdgcn_mfma_f32_16x16x32_bf16(a1, bfr[1][ks], acc[1], 0, 0, 0);
        acc[2] = __builtin_amdgcn_mfma_f32_16x16x32_bf16(a2, bfr[1][ks], acc[2], 0, 0, 0);
        acc[3] = __builtin_amdgcn_mfma_f32_16x16x32_bf16(a3, bfr[1][ks], acc[3], 0, 0, 0);
      }
    } else {
      #pragma unroll
      for (int ks = 0; ks < 4; ++ks) {
        const int cb = ((ks * 4 + kq) ^ mx7) << 4;
        #pragma unroll
        for (int i = 0; i < 5; ++i) {
          bf16x8 a = *(const bf16x8*)(bc + (64 + i * 16 + l15) * 256 + cb);
          acc[i] = __builtin_amdgcn_mfma_f32_16x16x32_bf16(a, bfr[0][ks], acc[i], 0, 0, 0);
        }
      }
    }

    // 3. convert + LDS-write next tile (loads have landed)
    if (have) stage_write(bn, clb, szl, scc, vf);

    // 4. store tile t (dense per-lane spans, non-temporal, full rows per WG)
    const int z0 = t * TM;
    if (h == 0) {
      #pragma unroll
      for (int r = 0; r < 4; ++r) {
        int z = z0 + (kq << 2) + r;
        float* orow = out + (size_t)z * ROWLEN;
        __builtin_nontemporal_store(acc[0][r], orow + n);
        f32x2u v2 = { acc[1][r], acc[2][r] };
        __builtin_nontemporal_store(v2, (f32x2u*)(orow + 128 + n * 3));
        __builtin_nontemporal_store(acc[3][r], orow + 128 + n * 3 + 2);
      }
    } else {
      #pragma unroll
      for (int r = 0; r < 4; ++r) {
        int z = z0 + (kq << 2) + r;
        float* orow = out + (size_t)z * ROWLEN;
        f32x4u v4 = { acc[0][r], acc[1][r], acc[2][r], acc[3][r] };
        __builtin_nontemporal_store(v4, (f32x4u*)(orow + 512 + n * 5));
        __builtin_nontemporal_store(acc[4][r], orow + 512 + n * 5 + 4);
      }
    }

    __syncthreads();
    cur ^= 1;
  }
}

extern "C" void kernel_launch(void* const* d_in, const int* in_sizes, int n_in,
                              void* d_out, int out_size, void* d_ws, size_t ws_size,
                              hipStream_t stream) {
  const float* x = (const float*)d_in[0];
  const float* w = (const float*)d_in[1];
  float* out = (float*)d_out;
  (void)in_sizes; (void)n_in; (void)out_size; (void)d_ws; (void)ws_size;
  dim3 grid(NWGS);
  dim3 block(1024);
  hipLaunchKernelGGL(linear_irreps_kernel, grid, block, 0, stream, x, w, out);
}

// Round 13
// 191.055 us; speedup vs baseline: 1.2270x; 1.0359x over previous
//
#include <hip/hip_runtime.h>
#include <stdint.h>

// irreps linear: 128x0e+128x1o+128x2e, per-block y[z,w,i] = a * sum_u W[u,w] x[z,u,i]
// r13 = r12 (fused full-row WGs, best known 197.9us) minus non-temporal store
// hints. r12 counters: FETCH 233MB (x half-resident in L3 across replays) but
// WRITE 668MB (1.45x ideal) -- NT forces every line to HBM, defeating L3
// write-back absorption and line-merging. Plain stores let L2/L3 merge the
// 192B/320B spans and absorb replay-to-replay overwrites.
// Structure: one 1024-thread WG owns 16 complete rows per tile (contiguous
// 73.7KB read + write), 1 WG/CU, W in regs, dbuf LDS, prefetch before MFMA,
// dense per-lane stores, one __syncthreads per tile.

#define NROWS 100000
#define ROWLEN 1152

typedef __attribute__((ext_vector_type(8))) short bf16x8;
typedef __attribute__((ext_vector_type(4))) float f32x4;
typedef __attribute__((ext_vector_type(4))) ushort u16x4;
typedef float f32x4u __attribute__((ext_vector_type(4), aligned(4)));
typedef float f32x2u __attribute__((ext_vector_type(2), aligned(4)));

__device__ __forceinline__ ushort f2b(float f) {
  union { float f; uint32_t u; } v; v.f = f;
  uint32_t r = v.u + 0x7FFFu + ((v.u >> 16) & 1u);  // RNE; inputs finite
  return (ushort)(r >> 16);
}

constexpr int TM     = 16;
constexpr int NTILES = NROWS / TM;   // 6250 exactly -> no guards anywhere
constexpr int NWGS   = 256;          // 1 WG/CU
constexpr int BUFB   = 144 * 256;    // 36864 B: 144 m-rows (16 D1 + 48 D3 + 80 D5)
constexpr float ALPHA = 0.088388347648318447f;  // 128^-0.5

// LDS byte for (m-row, 4-u chunk cc in 0..31), 8B granule; 16B-chunk XOR swizzle.
__device__ __forceinline__ int lbyte8(int m, int cc) {
  return m * 256 + ((((cc >> 1) ^ (m & 7)) << 4) | ((cc & 1) << 3));
}

// ---- staging: class A (tid<512): one D1 group + one D3 group; class B: one D5
// group. Group g: row szl = g>>5, u-chunk cc = g&31. Same per-lane patterns as r6.
__device__ __forceinline__ void stage_load(const float* __restrict__ x, int t,
                                           bool clb, int szl, int scc,
                                           f32x4 (&vf)[5])
{
  const float* row = x + (size_t)(t * TM + szl) * ROWLEN;
  if (!clb) {
    vf[0] = *(const f32x4*)(row + scc * 4);            // D1: u = 4cc..4cc+3
    const float* r3 = row + 128 + scc * 12;            // D3: 12 floats
    vf[1] = *(const f32x4*)(r3);
    vf[2] = *(const f32x4*)(r3 + 4);
    vf[3] = *(const f32x4*)(r3 + 8);
  } else {
    const float* r5 = row + 512 + scc * 20;            // D5: 20 floats
    #pragma unroll
    for (int j = 0; j < 5; ++j) vf[j] = *(const f32x4*)(r5 + 4 * j);
  }
}

__device__ __forceinline__ void stage_write(char* __restrict__ buf, bool clb,
                                            int szl, int scc, f32x4 (&vf)[5])
{
  if (!clb) {
    u16x4 p1;
    #pragma unroll
    for (int k = 0; k < 4; ++k) p1[k] = f2b(vf[0][k]);
    *(u16x4*)(buf + lbyte8(szl, scc)) = p1;            // D1: m = szl
    #pragma unroll
    for (int i = 0; i < 3; ++i) {                      // D3: m = 16 + i*16 + szl
      u16x4 pk;
      #pragma unroll
      for (int u = 0; u < 4; ++u) {
        int k = 3 * u + i;                             // compile-time
        pk[u] = f2b(vf[1 + (k >> 2)][k & 3]);
      }
      *(u16x4*)(buf + lbyte8(16 + i * 16 + szl, scc)) = pk;
    }
  } else {
    #pragma unroll
    for (int i = 0; i < 5; ++i) {                      // D5: m = 64 + i*16 + szl
      u16x4 pk;
      #pragma unroll
      for (int u = 0; u < 4; ++u) {
        int k = 5 * u + i;                             // compile-time
        pk[u] = f2b(vf[k >> 2][k & 3]);
      }
      *(u16x4*)(buf + lbyte8(64 + i * 16 + szl, scc)) = pk;
    }
  }
}

__global__ __launch_bounds__(1024, 4)
void linear_irreps_kernel(const float* __restrict__ x, const float* __restrict__ w,
                          float* __restrict__ out)
{
  __shared__ __align__(16) char lds[2 * BUFB];         // 73728 B

  const int tid  = threadIdx.x;
  const int lane = tid & 63;
  const int wv   = tid >> 6;            // 0..15
  const int l15  = lane & 15;
  const int kq   = (lane >> 4) & 3;
  const int kr   = kq << 3;
  const int mx7  = l15 & 7;             // (m & 7) for all m = base16 + l15
  const int h    = wv & 1;              // 0: D1+D3 m-tiles, 1: D5 m-tiles
  const int n    = ((wv >> 1) << 4) + l15;   // out/W column 0..127
  const bool clb = tid >= 512;
  const int sg   = clb ? tid - 512 : tid;
  const int szl  = sg >> 5;
  const int scc  = sg & 31;

  // ---- W -> registers once (ALPHA folded). h0: D1+D3 blocks; h1: D5 block.
  bf16x8 bfr[2][4];
  if (h == 0) {
    #pragma unroll
    for (int ks = 0; ks < 4; ++ks)
      #pragma unroll
      for (int j = 0; j < 8; ++j) {
        bfr[0][ks][j] = (short)f2b(w[(ks * 32 + kr + j) * 128 + n] * ALPHA);
        bfr[1][ks][j] = (short)f2b(w[16384 + (ks * 32 + kr + j) * 128 + n] * ALPHA);
      }
  } else {
    #pragma unroll
    for (int ks = 0; ks < 4; ++ks)
      #pragma unroll
      for (int j = 0; j < 8; ++j)
        bfr[0][ks][j] = (short)f2b(w[32768 + (ks * 32 + kr + j) * 128 + n] * ALPHA);
  }

  // ---- prologue: stage tile t0 ----
  const int t0 = blockIdx.x;
  f32x4 vf[5];
  stage_load(x, t0, clb, szl, scc, vf);
  stage_write(lds, clb, szl, scc, vf);
  __syncthreads();

  int cur = 0;
  for (int t = t0; t < NTILES; t += NWGS) {
    char* bc = lds + (cur ? BUFB : 0);
    char* bn = lds + (cur ? 0 : BUFB);
    const int tn = t + NWGS;
    const bool have = tn < NTILES;

    // 1. issue next tile's global loads (hide under MFMA)
    if (have) stage_load(x, tn, clb, szl, scc, vf);

    // 2. MFMA on current buffer
    f32x4 acc[5];
    #pragma unroll
    for (int i = 0; i < 5; ++i) acc[i] = f32x4{0.f, 0.f, 0.f, 0.f};
    if (h == 0) {
      #pragma unroll
      for (int ks = 0; ks < 4; ++ks) {
        const int cb = ((ks * 4 + kq) ^ mx7) << 4;
        bf16x8 a0 = *(const bf16x8*)(bc + (l15)       * 256 + cb);
        bf16x8 a1 = *(const bf16x8*)(bc + (16  + l15) * 256 + cb);
        bf16x8 a2 = *(const bf16x8*)(bc + (32  + l15) * 256 + cb);
        bf16x8 a3 = *(const bf16x8*)(bc + (48  + l15) * 256 + cb);
        acc[0] = __builtin_amdgcn_mfma_f32_16x16x32_bf16(a0, bfr[0][ks], acc[0], 0, 0, 0);
        acc[1] = __builtin_amdgcn_mfma_f32_16x16x32_bf16(a1, bfr[1][ks], acc[1], 0, 0, 0);
        acc[2] = __builtin_amdgcn_mfma_f32_16x16x32_bf16(a2, bfr[1][ks], acc[2], 0, 0, 0);
        acc[3] = __builtin_amdgcn_mfma_f32_16x16x32_bf16(a3, bfr[1][ks], acc[3], 0, 0, 0);
      }
    } else {
      #pragma unroll
      for (int ks = 0; ks < 4; ++ks) {
        const int cb = ((ks * 4 + kq) ^ mx7) << 4;
        #pragma unroll
        for (int i = 0; i < 5; ++i) {
          bf16x8 a = *(const bf16x8*)(bc + (64 + i * 16 + l15) * 256 + cb);
          acc[i] = __builtin_amdgcn_mfma_f32_16x16x32_bf16(a, bfr[0][ks], acc[i], 0, 0, 0);
        }
      }
    }

    // 3. convert + LDS-write next tile (loads have landed)
    if (have) stage_write(bn, clb, szl, scc, vf);

    // 4. store tile t (dense per-lane spans, plain stores -> L2/L3 merge &
    //    absorb; r12 showed NT hints inflate WRITE_SIZE 45% on this structure)
    const int z0 = t * TM;
    if (h == 0) {
      #pragma unroll
      for (int r = 0; r < 4; ++r) {
        int z = z0 + (kq << 2) + r;
        float* orow = out + (size_t)z * ROWLEN;
        orow[n] = acc[0][r];
        f32x2u v2 = { acc[1][r], acc[2][r] };
        *(f32x2u*)(orow + 128 + n * 3) = v2;
        orow[128 + n * 3 + 2] = acc[3][r];
      }
    } else {
      #pragma unroll
      for (int r = 0; r < 4; ++r) {
        int z = z0 + (kq << 2) + r;
        float* orow = out + (size_t)z * ROWLEN;
        f32x4u v4 = { acc[0][r], acc[1][r], acc[2][r], acc[3][r] };
        *(f32x4u*)(orow + 512 + n * 5) = v4;
        orow[512 + n * 5 + 4] = acc[4][r];
      }
    }

    __syncthreads();
    cur ^= 1;
  }
}

extern "C" void kernel_launch(void* const* d_in, const int* in_sizes, int n_in,
                              void* d_out, int out_size, void* d_ws, size_t ws_size,
                              hipStream_t stream) {
  const float* x = (const float*)d_in[0];
  const float* w = (const float*)d_in[1];
  float* out = (float*)d_out;
  (void)in_sizes; (void)n_in; (void)out_size; (void)d_ws; (void)ws_size;
  dim3 grid(NWGS);
  dim3 block(1024);
  hipLaunchKernelGGL(linear_irreps_kernel, grid, block, 0, stream, x, w, out);
}